// Round 1
// baseline (604.020 us; speedup 1.0000x reference)
//
#include <hip/hip_runtime.h>

#define T_STEPS 512
#define F_IN    64
#define HID     20
#define G4      80    // 4*HID gates per batch element
#define BT      4     // batch tile per block
#define NTHREADS 320  // BT*G4, 5 waves
#define NCLS    10

__device__ __forceinline__ float sigf(float x) {
    // 1/(1+e^-x); rcp(inf)=0 and exp overflow saturate correctly
    return __builtin_amdgcn_rcpf(1.0f + __expf(-x));
}
__device__ __forceinline__ float tanh_fast(float x) {
    // 1 - 2/(e^{2x}+1); saturates to +/-1 correctly
    float e = __expf(2.0f * x);
    return 1.0f - 2.0f * __builtin_amdgcn_rcpf(e + 1.0f);
}

extern "C" __global__ __launch_bounds__(NTHREADS)
void lstm_fused(const float* __restrict__ x,
                const float* __restrict__ W_ih0, const float* __restrict__ W_hh0,
                const float* __restrict__ b0,
                const float* __restrict__ W_ih1, const float* __restrict__ W_hh1,
                const float* __restrict__ b1,
                const float* __restrict__ W_fc, const float* __restrict__ b_fc,
                float* __restrict__ out)
{
    __shared__ float xs[BT * F_IN];     // staged x_t for the 4 batch rows
    __shared__ float h0s[BT * HID];
    __shared__ float h1s[BT * HID];
    __shared__ float gs[BT * G4];       // activated gates (reused by both layers)

    const int tid = threadIdx.x;
    const int bg  = blockIdx.x;               // 0..255, batch base = bg*BT
    const int b   = tid / G4;                 // 0..3
    const int g   = tid - b * G4;             // 0..79  (gate index, PyTorch order i,f,g,o)
    const bool isG = (g >= 2 * HID) && (g < 3 * HID);

    // ---- per-thread weight columns in registers ----
    float wx[F_IN];                // W_ih0 row g (== column g of W_ih0^T)
    float wh0[HID], wi1[HID], wh1[HID];
    float bias0, bias1;
    {
        const float4* p = (const float4*)(W_ih0 + g * F_IN);
        #pragma unroll
        for (int k = 0; k < F_IN / 4; ++k) ((float4*)wx)[k] = p[k];
        const float4* p2 = (const float4*)(W_hh0 + g * HID);
        #pragma unroll
        for (int k = 0; k < HID / 4; ++k) ((float4*)wh0)[k] = p2[k];
        const float4* p3 = (const float4*)(W_ih1 + g * HID);
        #pragma unroll
        for (int k = 0; k < HID / 4; ++k) ((float4*)wi1)[k] = p3[k];
        const float4* p4 = (const float4*)(W_hh1 + g * HID);
        #pragma unroll
        for (int k = 0; k < HID / 4; ++k) ((float4*)wh1)[k] = p4[k];
        bias0 = b0[g];
        bias1 = b1[g];
    }

    // state-update thread mapping (tid < 80)
    const int ub = tid / HID;
    const int uh = tid - ub * HID;
    float c0 = 0.f, c1 = 0.f;

    // FC thread mapping (tid < 40): 4 batch x 10 classes
    const int fb  = tid / NCLS;
    const int fcc = tid - fb * NCLS;
    float facc = 0.f;

    if (tid < BT * HID) { h0s[tid] = 0.f; h1s[tid] = 0.f; }

    // x prefetch: threads 0..255 each own one (b,f) element per step
    const int xb = tid >> 6;
    const int xf = tid & 63;
    const float* xptr = x + ((size_t)(bg * BT + xb) * T_STEPS) * F_IN + xf;
    float xreg = 0.f;
    if (tid < 256) xreg = xptr[0];

    for (int t = 0; t < T_STEPS; ++t) {
        if (tid < 256) xs[tid] = xreg;

        // prefetch W_fc row slice for this t (consumed after B5 -> latency hidden)
        float4 wf[HID / 4];
        if (tid < BT * NCLS) {
            const float4* wp = (const float4*)(W_fc + (size_t)fcc * (T_STEPS * HID) + t * HID);
            #pragma unroll
            for (int k = 0; k < HID / 4; ++k) wf[k] = wp[k];
        }
        __syncthreads();                                   // B1: xs ready

        // prefetch next x (consumed at top of next iter -> hidden under full step)
        if (tid < 256 && t + 1 < T_STEPS) xreg = xptr[(size_t)(t + 1) * F_IN];

        // ---- layer0 gates: one gate per thread ----
        {
            float acc = bias0;
            const float* xrow = xs + b * F_IN;
            #pragma unroll
            for (int f2 = 0; f2 < F_IN; ++f2) acc += xrow[f2] * wx[f2];
            const float* h0row = h0s + b * HID;
            #pragma unroll
            for (int h = 0; h < HID; ++h) acc += h0row[h] * wh0[h];
            gs[tid] = isG ? tanh_fast(acc) : sigf(acc);
        }
        __syncthreads();                                   // B2: gates0 ready

        if (tid < BT * HID) {
            float iv = gs[ub * G4 + uh];
            float fv = gs[ub * G4 + HID + uh];
            float gv = gs[ub * G4 + 2 * HID + uh];
            float ov = gs[ub * G4 + 3 * HID + uh];
            c0 = fv * c0 + iv * gv;
            h0s[tid] = ov * tanh_fast(c0);
        }
        __syncthreads();                                   // B3: h0 updated

        // ---- layer1 gates ----
        {
            float acc1 = bias1;
            const float* h0row = h0s + b * HID;
            const float* h1row = h1s + b * HID;
            #pragma unroll
            for (int h = 0; h < HID; ++h) acc1 += h0row[h] * wi1[h];
            #pragma unroll
            for (int h = 0; h < HID; ++h) acc1 += h1row[h] * wh1[h];
            gs[tid] = isG ? tanh_fast(acc1) : sigf(acc1);
        }
        __syncthreads();                                   // B4: gates1 ready

        if (tid < BT * HID) {
            float iv = gs[ub * G4 + uh];
            float fv = gs[ub * G4 + HID + uh];
            float gv = gs[ub * G4 + 2 * HID + uh];
            float ov = gs[ub * G4 + 3 * HID + uh];
            c1 = fv * c1 + iv * gv;
            h1s[tid] = ov * tanh_fast(c1);
        }
        __syncthreads();                                   // B5: h1 updated

        // ---- FC accumulation for this t ----
        if (tid < BT * NCLS) {
            const float* hr = h1s + fb * HID;
            const float* wr = (const float*)wf;
            #pragma unroll
            for (int h = 0; h < HID; ++h) facc += hr[h] * wr[h];
        }
        // no barrier needed: next write to h1s is after B4 of next iteration
    }

    if (tid < BT * NCLS) {
        out[(bg * BT + fb) * NCLS + fcc] = facc + b_fc[fcc];
    }
}

extern "C" void kernel_launch(void* const* d_in, const int* in_sizes, int n_in,
                              void* d_out, int out_size, void* d_ws, size_t ws_size,
                              hipStream_t stream) {
    const float* x     = (const float*)d_in[0];
    const float* W_ih0 = (const float*)d_in[1];
    const float* W_hh0 = (const float*)d_in[2];
    const float* b0    = (const float*)d_in[3];
    const float* W_ih1 = (const float*)d_in[4];
    const float* W_hh1 = (const float*)d_in[5];
    const float* b1    = (const float*)d_in[6];
    const float* W_fc  = (const float*)d_in[7];
    const float* b_fc  = (const float*)d_in[8];
    float* out = (float*)d_out;

    lstm_fused<<<dim3(256), dim3(NTHREADS), 0, stream>>>(
        x, W_ih0, W_hh0, b0, W_ih1, W_hh1, b1, W_fc, b_fc, out);
}